// Round 1
// baseline (678.247 us; speedup 1.0000x reference)
//
#include <hip/hip_runtime.h>
#include <hip/hip_bf16.h>
#include <cmath>

typedef float f32x4 __attribute__((ext_vector_type(4)));
typedef __bf16 bf16x8 __attribute__((ext_vector_type(8)));

#define WS_SZ 7
#define SHIFT 3
#define HGRID 56
#define C_DIM 192
#define NHEADS 6
#define HDIM 32
#define NTOK 100352   // 32 * 3136
#define NWIN 2048     // 32 * 8 * 8

// map window-space row (w*49+i) -> original token index (inverse roll by +SHIFT)
__device__ __forceinline__ int win_to_tok(int wrow) {
    int w = wrow / 49, i = wrow - w * 49;
    int b = w >> 6, rem = w & 63;
    int wy = rem >> 3, wx = rem & 7;
    int yi = i / 7, xi = i - yi * 7;
    int y = wy * 7 + yi + SHIFT; if (y >= HGRID) y -= HGRID;
    int x = wx * 7 + xi + SHIFT; if (x >= HGRID) x -= HGRID;
    return b * (HGRID * HGRID) + y * HGRID + x;
}

// ---------------- LayerNorm (one wave per token) ----------------
// WINDOWED=1: gather from rolled position, write window-partitioned rows.
template<int WINDOWED>
__global__ __launch_bounds__(256)
void ln_kernel(const float* __restrict__ x, const float* __restrict__ w,
               const float* __restrict__ b, __bf16* __restrict__ out)
{
    int r = blockIdx.x * 4 + (threadIdx.x >> 6);
    int lane = threadIdx.x & 63;
    int src = WINDOWED ? win_to_tok(r) : r;
    const float* xp = x + (size_t)src * C_DIM;
    float v0 = xp[lane], v1 = xp[lane + 64], v2 = xp[lane + 128];
    float s = v0 + v1 + v2;
    float sq = v0 * v0 + v1 * v1 + v2 * v2;
    #pragma unroll
    for (int off = 32; off; off >>= 1) {
        s  += __shfl_xor(s, off);
        sq += __shfl_xor(sq, off);
    }
    float mu = s * (1.f / C_DIM);
    float rs = rsqrtf(sq * (1.f / C_DIM) - mu * mu + 1e-5f);
    __bf16* op = out + (size_t)r * C_DIM;
    op[lane]       = (__bf16)((v0 - mu) * rs * w[lane]       + b[lane]);
    op[lane + 64]  = (__bf16)((v1 - mu) * rs * w[lane + 64]  + b[lane + 64]);
    op[lane + 128] = (__bf16)((v2 - mu) * rs * w[lane + 128] + b[lane + 128]);
}

// ---------------- GEMM: out = A(bf16, MxK) @ W(fp32, NxK)^T + bias ----------------
// 128x64 tile per 256-thread block; 4 waves as 2x2; wave computes 64x32 via
// 4x2 frags of mfma_f32_16x16x32_bf16.
// MODE 0: store bf16 (QKV). MODE 1: window-reverse scatter + residual -> fp32 out.
// MODE 2: GELU -> bf16. MODE 3: out += acc+bias (fp32 RMW).
template<int MODE>
__global__ __launch_bounds__(256)
void gemm_kernel(const __bf16* __restrict__ A, const float* __restrict__ W,
                 const float* __restrict__ bias, void* __restrict__ outp,
                 const float* __restrict__ resid, int N, int K)
{
    __shared__ __bf16 As[128 * 40];
    __shared__ __bf16 Bs[64 * 40];
    const int tid = threadIdx.x;
    const int wave = tid >> 6, lane = tid & 63;
    const int wm = wave >> 1, wn = wave & 1;
    const int l15 = lane & 15, q8 = (lane >> 4) << 3;
    const int m0 = blockIdx.x * 128, n0 = blockIdx.y * 64;

    f32x4 acc[4][2];
    f32x4 zero = {0.f, 0.f, 0.f, 0.f};
    #pragma unroll
    for (int i = 0; i < 4; i++)
        #pragma unroll
        for (int j = 0; j < 2; j++) acc[i][j] = zero;

    const int br = tid >> 2, bc = (tid & 3) << 3;
    for (int kt = 0; kt < K; kt += 32) {
        __syncthreads();
        // stage A: 128x32 bf16 (2 x 16B per thread)
        #pragma unroll
        for (int it = 0; it < 2; it++) {
            int idx = it * 256 + tid;
            int r = idx >> 2, c = (idx & 3) << 3;
            *(uint4*)(&As[r * 40 + c]) =
                *(const uint4*)(A + (size_t)(m0 + r) * K + kt + c);
        }
        // stage B: 64x32, fp32 -> bf16
        {
            const float* src = W + (size_t)(n0 + br) * K + kt + bc;
            float4 f0 = *(const float4*)src;
            float4 f1 = *(const float4*)(src + 4);
            bf16x8 vb;
            vb[0] = (__bf16)f0.x; vb[1] = (__bf16)f0.y;
            vb[2] = (__bf16)f0.z; vb[3] = (__bf16)f0.w;
            vb[4] = (__bf16)f1.x; vb[5] = (__bf16)f1.y;
            vb[6] = (__bf16)f1.z; vb[7] = (__bf16)f1.w;
            *(bf16x8*)(&Bs[br * 40 + bc]) = vb;
        }
        __syncthreads();
        bf16x8 af[4], bfr[2];
        #pragma unroll
        for (int fm = 0; fm < 4; fm++)
            af[fm] = *(const bf16x8*)(&As[(wm * 64 + fm * 16 + l15) * 40 + q8]);
        #pragma unroll
        for (int fn = 0; fn < 2; fn++)
            bfr[fn] = *(const bf16x8*)(&Bs[(wn * 32 + fn * 16 + l15) * 40 + q8]);
        #pragma unroll
        for (int fm = 0; fm < 4; fm++)
            #pragma unroll
            for (int fn = 0; fn < 2; fn++)
                acc[fm][fn] = __builtin_amdgcn_mfma_f32_16x16x32_bf16(
                    af[fm], bfr[fn], acc[fm][fn], 0, 0, 0);
    }

    const int l4 = lane >> 4;
    #pragma unroll
    for (int fm = 0; fm < 4; fm++) {
        #pragma unroll
        for (int fn = 0; fn < 2; fn++) {
            int c = n0 + wn * 32 + fn * 16 + l15;
            float bv = bias[c];
            #pragma unroll
            for (int r = 0; r < 4; r++) {
                int m = m0 + wm * 64 + fm * 16 + l4 * 4 + r;
                float v = acc[fm][fn][r] + bv;
                if (MODE == 0) {
                    ((__bf16*)outp)[(size_t)m * N + c] = (__bf16)v;
                } else if (MODE == 2) {
                    float g = 0.5f * v * (1.f + erff(v * 0.70710678118654752f));
                    ((__bf16*)outp)[(size_t)m * N + c] = (__bf16)g;
                } else if (MODE == 1) {
                    int t = win_to_tok(m);
                    ((float*)outp)[(size_t)t * C_DIM + c] =
                        resid[(size_t)t * C_DIM + c] + v;
                } else {
                    float* p = (float*)outp + (size_t)m * C_DIM + c;
                    *p = *p + v;
                }
            }
        }
    }
}

// ---------------- Windowed attention: one wave per (window, head) ----------------
__global__ __launch_bounds__(64)
void attn_kernel(const __bf16* __restrict__ qkv, const float* __restrict__ rpb,
                 __bf16* __restrict__ out)
{
    const int w = blockIdx.x;     // window
    const int head = blockIdx.y;  // head
    const int lane = threadIdx.x;
    __shared__ float ks[49 * 32];
    __shared__ float vs[49 * 32];
    __shared__ float rp[169];
    __shared__ float Sb[64 * 49];

    const size_t base = (size_t)w * 49 * 576 + head * 32;
    // stage K, V (49x32 each) as fp32
    for (int chunk = lane; chunk < 196; chunk += 64) {
        int r = chunk >> 2, c = (chunk & 3) << 3;
        bf16x8 kv = *(const bf16x8*)(qkv + base + (size_t)r * 576 + 192 + c);
        bf16x8 vv = *(const bf16x8*)(qkv + base + (size_t)r * 576 + 384 + c);
        #pragma unroll
        for (int u = 0; u < 8; u++) {
            ks[r * 32 + c + u] = (float)kv[u];
            vs[r * 32 + c + u] = (float)vv[u];
        }
    }
    for (int idx = lane; idx < 169; idx += 64)
        rp[idx] = rpb[idx * NHEADS + head];
    __syncthreads();

    if (lane < 49) {
        const float scale = 0.17677669529663687f;  // 1/sqrt(32)
        float q[32];
        const bf16x8* qp = (const bf16x8*)(qkv + base + (size_t)lane * 576);
        #pragma unroll
        for (int c8 = 0; c8 < 4; c8++) {
            bf16x8 qv = qp[c8];
            #pragma unroll
            for (int u = 0; u < 8; u++) q[c8 * 8 + u] = (float)qv[u] * scale;
        }
        int yi = lane / 7, xi = lane - yi * 7;
        float mx = -1e30f;
        for (int j = 0; j < 49; j++) {
            float acc = 0.f;
            const float4* kp = (const float4*)(ks + j * 32);
            #pragma unroll
            for (int c4 = 0; c4 < 8; c4++) {
                float4 kv = kp[c4];
                acc += q[c4 * 4 + 0] * kv.x + q[c4 * 4 + 1] * kv.y +
                       q[c4 * 4 + 2] * kv.z + q[c4 * 4 + 3] * kv.w;
            }
            int yj = j / 7, xj = j - yj * 7;
            acc += rp[(yi - yj + 6) * 13 + (xi - xj + 6)];
            Sb[lane * 49 + j] = acc;
            mx = fmaxf(mx, acc);
        }
        float sum = 0.f;
        for (int j = 0; j < 49; j++) {
            float e = __expf(Sb[lane * 49 + j] - mx);
            Sb[lane * 49 + j] = e;
            sum += e;
        }
        float inv = 1.f / sum;
        float O[32];
        #pragma unroll
        for (int c = 0; c < 32; c++) O[c] = 0.f;
        for (int j = 0; j < 49; j++) {
            float p = Sb[lane * 49 + j];
            const float4* vp = (const float4*)(vs + j * 32);
            #pragma unroll
            for (int c4 = 0; c4 < 8; c4++) {
                float4 vv = vp[c4];
                O[c4 * 4 + 0] += p * vv.x; O[c4 * 4 + 1] += p * vv.y;
                O[c4 * 4 + 2] += p * vv.z; O[c4 * 4 + 3] += p * vv.w;
            }
        }
        __bf16* op = out + (size_t)(w * 49 + lane) * C_DIM + head * 32;
        #pragma unroll
        for (int c8 = 0; c8 < 4; c8++) {
            bf16x8 ov;
            #pragma unroll
            for (int u = 0; u < 8; u++) ov[u] = (__bf16)(O[c8 * 8 + u] * inv);
            *(bf16x8*)(op + c8 * 8) = ov;
        }
    }
}

extern "C" void kernel_launch(void* const* d_in, const int* in_sizes, int n_in,
                              void* d_out, int out_size, void* d_ws, size_t ws_size,
                              hipStream_t stream) {
    const float* x     = (const float*)d_in[0];
    const float* n1w   = (const float*)d_in[1];
    const float* n1b   = (const float*)d_in[2];
    const float* qkvw  = (const float*)d_in[3];
    const float* qkvb  = (const float*)d_in[4];
    const float* rpb   = (const float*)d_in[5];
    const float* projw = (const float*)d_in[6];
    const float* projb = (const float*)d_in[7];
    const float* n2w   = (const float*)d_in[8];
    const float* n2b   = (const float*)d_in[9];
    const float* fc1w  = (const float*)d_in[10];
    const float* fc1b  = (const float*)d_in[11];
    const float* fc2w  = (const float*)d_in[12];
    const float* fc2b  = (const float*)d_in[13];
    float* out = (float*)d_out;
    char* ws = (char*)d_ws;

    // bufA: 100352*192 bf16 (hw / attn_out / h2, serially reused) = 38,535,168 B
    // bufQ: 100352*576 bf16 (qkv), bufH: 100352*768 bf16 (mlp hidden) — same
    // offset, qkv is dead before hidden is written. Total ws: 192,675,840 B.
    __bf16* bufA = (__bf16*)ws;
    __bf16* bufQ = (__bf16*)(ws + 38535168);
    __bf16* bufH = (__bf16*)(ws + 38535168);

    // 1. LN1 + shift + window partition
    ln_kernel<1><<<NTOK / 4, 256, 0, stream>>>(x, n1w, n1b, bufA);
    // 2. QKV GEMM: (100352,192)x(192,576)
    gemm_kernel<0><<<dim3(NTOK / 128, 9), 256, 0, stream>>>(
        bufA, qkvw, qkvb, bufQ, nullptr, 576, 192);
    // 3. windowed attention
    attn_kernel<<<dim3(NWIN, NHEADS), 64, 0, stream>>>(bufQ, rpb, bufA);
    // 4. proj GEMM + window reverse + residual -> d_out (= x2)
    gemm_kernel<1><<<dim3(NTOK / 128, 3), 256, 0, stream>>>(
        bufA, projw, projb, (void*)out, x, 192, 192);
    // 5. LN2
    ln_kernel<0><<<NTOK / 4, 256, 0, stream>>>(out, n2w, n2b, bufA);
    // 6. FC1 + GELU
    gemm_kernel<2><<<dim3(NTOK / 128, 12), 256, 0, stream>>>(
        bufA, fc1w, fc1b, bufH, nullptr, 768, 192);
    // 7. FC2 + residual (d_out += mlp)
    gemm_kernel<3><<<dim3(NTOK / 128, 3), 256, 0, stream>>>(
        bufH, fc2w, fc2b, (void*)out, nullptr, 192, 768);
}

// Round 4
// 569.749 us; speedup vs baseline: 1.1904x; 1.1904x over previous
//
#include <hip/hip_runtime.h>
#include <hip/hip_bf16.h>
#include <cmath>

typedef float f32x4 __attribute__((ext_vector_type(4)));
typedef __bf16 bf16x8 __attribute__((ext_vector_type(8)));

#define WS_SZ 7
#define SHIFT 3
#define HGRID 56
#define C_DIM 192
#define NHEADS 6
#define HDIM 32
#define NTOK 100352   // 32 * 3136
#define NWIN 2048     // 32 * 8 * 8

// map window-space row (w*49+i) -> original token index (inverse roll by +SHIFT)
__device__ __forceinline__ int win_to_tok(int wrow) {
    int w = wrow / 49, i = wrow - w * 49;
    int b = w >> 6, rem = w & 63;
    int wy = rem >> 3, wx = rem & 7;
    int yi = i / 7, xi = i - yi * 7;
    int y = wy * 7 + yi + SHIFT; if (y >= HGRID) y -= HGRID;
    int x = wx * 7 + xi + SHIFT; if (x >= HGRID) x -= HGRID;
    return b * (HGRID * HGRID) + y * HGRID + x;
}

// ---------------- fp32 -> bf16 weight conversion (8 elems/thread) ----------------
__global__ __launch_bounds__(256)
void cvt_kernel(const float* __restrict__ src, __bf16* __restrict__ dst, int n8)
{
    int idx = blockIdx.x * 256 + threadIdx.x;
    if (idx >= n8) return;
    float4 a = ((const float4*)src)[idx * 2];
    float4 b = ((const float4*)src)[idx * 2 + 1];
    bf16x8 o;
    o[0] = (__bf16)a.x; o[1] = (__bf16)a.y; o[2] = (__bf16)a.z; o[3] = (__bf16)a.w;
    o[4] = (__bf16)b.x; o[5] = (__bf16)b.y; o[6] = (__bf16)b.z; o[7] = (__bf16)b.w;
    ((bf16x8*)dst)[idx] = o;
}

// ---------------- expand rel-pos bias -> bias_g[head][49][49] fp32 ----------------
__global__ __launch_bounds__(256)
void bias_expand_kernel(const float* __restrict__ rpb, float* __restrict__ bias_g)
{
    int idx = blockIdx.x * 256 + threadIdx.x;
    if (idx >= NHEADS * 2401) return;
    int h = idx / 2401, rem = idx - h * 2401;
    int i = rem / 49, j = rem - i * 49;
    int yi = i / 7, xi = i - yi * 7;
    int yj = j / 7, xj = j - yj * 7;
    int ri = (yi - yj + 6) * 13 + (xi - xj + 6);
    bias_g[idx] = rpb[ri * NHEADS + h];
}

// ---------------- LayerNorm (one wave per token) ----------------
template<int WINDOWED>
__global__ __launch_bounds__(256)
void ln_kernel(const float* __restrict__ x, const float* __restrict__ w,
               const float* __restrict__ b, __bf16* __restrict__ out)
{
    int r = blockIdx.x * 4 + (threadIdx.x >> 6);
    int lane = threadIdx.x & 63;
    int src = WINDOWED ? win_to_tok(r) : r;
    const float* xp = x + (size_t)src * C_DIM;
    float v0 = xp[lane], v1 = xp[lane + 64], v2 = xp[lane + 128];
    float s = v0 + v1 + v2;
    float sq = v0 * v0 + v1 * v1 + v2 * v2;
    #pragma unroll
    for (int off = 32; off; off >>= 1) {
        s  += __shfl_xor(s, off);
        sq += __shfl_xor(sq, off);
    }
    float mu = s * (1.f / C_DIM);
    float rs = rsqrtf(sq * (1.f / C_DIM) - mu * mu + 1e-5f);
    __bf16* op = out + (size_t)r * C_DIM;
    op[lane]       = (__bf16)((v0 - mu) * rs * w[lane]       + b[lane]);
    op[lane + 64]  = (__bf16)((v1 - mu) * rs * w[lane + 64]  + b[lane + 64]);
    op[lane + 128] = (__bf16)((v2 - mu) * rs * w[lane + 128] + b[lane + 128]);
}

// ---------------- GEMM: out = A(bf16, MxK) @ W(NxK)^T + bias ----------------
// WBF16: W is pre-converted bf16; else fp32 (converted in staging, R1-proven).
// MODE 0: store bf16. MODE 1: window-reverse scatter + residual -> fp32.
// MODE 2: GELU -> bf16. MODE 3: out += acc+bias (fp32 RMW).
template<int MODE, int WBF16>
__global__ __launch_bounds__(256)
void gemm_kernel(const __bf16* __restrict__ A, const void* __restrict__ W,
                 const float* __restrict__ bias, void* __restrict__ outp,
                 const float* __restrict__ resid, int N, int K)
{
    __shared__ __bf16 As[128 * 40];
    __shared__ __bf16 Bs[64 * 40];
    const int tid = threadIdx.x;
    const int wave = tid >> 6, lane = tid & 63;
    const int wm = wave >> 1, wn = wave & 1;
    const int l15 = lane & 15, q8 = (lane >> 4) << 3;
    const int m0 = blockIdx.x * 128, n0 = blockIdx.y * 64;

    f32x4 acc[4][2];
    f32x4 zero = {0.f, 0.f, 0.f, 0.f};
    #pragma unroll
    for (int i = 0; i < 4; i++)
        #pragma unroll
        for (int j = 0; j < 2; j++) acc[i][j] = zero;

    const int br = tid >> 2, bc = (tid & 3) << 3;
    for (int kt = 0; kt < K; kt += 32) {
        __syncthreads();
        // stage A: 128x32 bf16 (2 x 16B per thread)
        #pragma unroll
        for (int it = 0; it < 2; it++) {
            int idx = it * 256 + tid;
            int r = idx >> 2, c = (idx & 3) << 3;
            *(uint4*)(&As[r * 40 + c]) =
                *(const uint4*)(A + (size_t)(m0 + r) * K + kt + c);
        }
        // stage B: 64x32
        if (WBF16) {
            *(uint4*)(&Bs[br * 40 + bc]) =
                *(const uint4*)((const __bf16*)W + (size_t)(n0 + br) * K + kt + bc);
        } else {
            const float* src = (const float*)W + (size_t)(n0 + br) * K + kt + bc;
            float4 f0 = *(const float4*)src;
            float4 f1 = *(const float4*)(src + 4);
            bf16x8 vb;
            vb[0] = (__bf16)f0.x; vb[1] = (__bf16)f0.y;
            vb[2] = (__bf16)f0.z; vb[3] = (__bf16)f0.w;
            vb[4] = (__bf16)f1.x; vb[5] = (__bf16)f1.y;
            vb[6] = (__bf16)f1.z; vb[7] = (__bf16)f1.w;
            *(bf16x8*)(&Bs[br * 40 + bc]) = vb;
        }
        __syncthreads();
        bf16x8 af[4], bfr[2];
        #pragma unroll
        for (int fm = 0; fm < 4; fm++)
            af[fm] = *(const bf16x8*)(&As[(wm * 64 + fm * 16 + l15) * 40 + q8]);
        #pragma unroll
        for (int fn = 0; fn < 2; fn++)
            bfr[fn] = *(const bf16x8*)(&Bs[(wn * 32 + fn * 16 + l15) * 40 + q8]);
        #pragma unroll
        for (int fm = 0; fm < 4; fm++)
            #pragma unroll
            for (int fn = 0; fn < 2; fn++)
                acc[fm][fn] = __builtin_amdgcn_mfma_f32_16x16x32_bf16(
                    af[fm], bfr[fn], acc[fm][fn], 0, 0, 0);
    }

    const int l4 = lane >> 4;
    #pragma unroll
    for (int fm = 0; fm < 4; fm++) {
        #pragma unroll
        for (int fn = 0; fn < 2; fn++) {
            int c = n0 + wn * 32 + fn * 16 + l15;
            float bv = bias[c];
            #pragma unroll
            for (int r = 0; r < 4; r++) {
                int m = m0 + wm * 64 + fm * 16 + l4 * 4 + r;
                float v = acc[fm][fn][r] + bv;
                if (MODE == 0) {
                    ((__bf16*)outp)[(size_t)m * N + c] = (__bf16)v;
                } else if (MODE == 2) {
                    float g = 0.5f * v * (1.f + erff(v * 0.70710678118654752f));
                    ((__bf16*)outp)[(size_t)m * N + c] = (__bf16)g;
                } else if (MODE == 1) {
                    int t = win_to_tok(m);
                    ((float*)outp)[(size_t)t * C_DIM + c] =
                        resid[(size_t)t * C_DIM + c] + v;
                } else {
                    float* p = (float*)outp + (size_t)m * C_DIM + c;
                    *p = *p + v;
                }
            }
        }
    }
}

// ---------------- MFMA windowed attention: one wave per (window, head) ----------------
__global__ __launch_bounds__(256, 2)
void attn_mfma_kernel(const __bf16* __restrict__ qkv,
                      const float* __restrict__ bias_g,
                      __bf16* __restrict__ out)
{
    const int wave = threadIdx.x >> 6;
    const int lane = threadIdx.x & 63;
    const int pair = blockIdx.x * 4 + wave;       // 12288 pairs
    const int w = pair / 6, head = pair - (pair / 6) * 6;

    __shared__ __bf16 vsT_s[4][32 * 72];          // V^T: [d][j], stride 72
    __shared__ __bf16 Ps_s[4][64 * 72];           // P:   [i][j], stride 72
    __bf16* vsT = vsT_s[wave];
    __bf16* Ps  = Ps_s[wave];

    const int l15 = lane & 15, q4 = lane >> 4, q8 = q4 << 3;
    const size_t qbase = (size_t)w * 49 * 576 + head * 32;

    // stage V transposed: vsT[d][j] = V[j][d]; zero k-padding j in [49,64)
    {
        int d = lane & 31, jh = lane >> 5;
        #pragma unroll
        for (int it = 0; it < 25; ++it) {
            int j = it * 2 + jh;
            if (j < 49)
                vsT[d * 72 + j] = qkv[qbase + (size_t)j * 576 + 384 + d];
        }
        for (int idx = lane; idx < 32 * 15; idx += 64) {
            int dd = idx / 15, jj = 49 + (idx - dd * 15);
            vsT[dd * 72 + jj] = (__bf16)0.f;
        }
    }

    // Q/K A/B frags direct from global (row clamp 48; clamped rows masked later)
    bf16x8 qf[4], kf[4];
    #pragma unroll
    for (int t = 0; t < 4; ++t) {
        int row = t * 16 + l15;
        int rq = row < 49 ? row : 48;
        qf[t] = *(const bf16x8*)(qkv + qbase + (size_t)rq * 576 + q8);
        kf[t] = *(const bf16x8*)(qkv + qbase + (size_t)rq * 576 + 192 + q8);
    }

    f32x4 sc[4][4];
    f32x4 zero = {0.f, 0.f, 0.f, 0.f};
    #pragma unroll
    for (int tm = 0; tm < 4; ++tm)
        #pragma unroll
        for (int tn = 0; tn < 4; ++tn) sc[tm][tn] = zero;
    #pragma unroll
    for (int tm = 0; tm < 4; ++tm)
        #pragma unroll
        for (int tn = 0; tn < 4; ++tn)
            sc[tm][tn] = __builtin_amdgcn_mfma_f32_16x16x32_bf16(
                qf[tm], kf[tn], sc[tm][tn], 0, 0, 0);

    // softmax over rows (C layout: col = l15 + 16*tn, row = tm*16 + q4*4 + r)
    const float scale = 0.17677669529663687f;      // 1/sqrt(32)
    const int hbase = head * 2401;
    #pragma unroll
    for (int tm = 0; tm < 4; ++tm) {
        #pragma unroll
        for (int r = 0; r < 4; ++r) {
            int i = tm * 16 + q4 * 4 + r;
            int ioff = hbase + (i < 49 ? i : 48) * 49;
            float v[4];
            #pragma unroll
            for (int tn = 0; tn < 4; ++tn) {
                int j = tn * 16 + l15;
                float bz = (j < 49) ? bias_g[ioff + (j < 49 ? j : 0)] : 0.f;
                float t = sc[tm][tn][r] * scale + bz;
                v[tn] = (j < 49) ? t : -1e30f;
            }
            float mx = fmaxf(fmaxf(v[0], v[1]), fmaxf(v[2], v[3]));
            mx = fmaxf(mx, __shfl_xor(mx, 1));
            mx = fmaxf(mx, __shfl_xor(mx, 2));
            mx = fmaxf(mx, __shfl_xor(mx, 4));
            mx = fmaxf(mx, __shfl_xor(mx, 8));
            float sm = 0.f;
            #pragma unroll
            for (int tn = 0; tn < 4; ++tn) {
                float e = __expf(v[tn] - mx);
                sc[tm][tn][r] = e;
                sm += e;
            }
            sm += __shfl_xor(sm, 1);
            sm += __shfl_xor(sm, 2);
            sm += __shfl_xor(sm, 4);
            sm += __shfl_xor(sm, 8);
            float inv = 1.f / sm;
            if (i < 49) {
                #pragma unroll
                for (int tn = 0; tn < 4; ++tn) {
                    int j = tn * 16 + l15;
                    Ps[i * 72 + j] = (__bf16)((j < 49) ? sc[tm][tn][r] * inv : 0.f);
                }
            }
        }
    }

    __syncthreads();

    // O = P * V : A = P[m][k=j], B = vsT[n=d][k=j]
    f32x4 oc[4][2];
    #pragma unroll
    for (int tm = 0; tm < 4; ++tm)
        #pragma unroll
        for (int tn = 0; tn < 2; ++tn) oc[tm][tn] = zero;
    #pragma unroll
    for (int ks = 0; ks < 2; ++ks) {
        bf16x8 bv[2];
        #pragma unroll
        for (int tn = 0; tn < 2; ++tn)
            bv[tn] = *(const bf16x8*)(vsT + (tn * 16 + l15) * 72 + ks * 32 + q8);
        #pragma unroll
        for (int tm = 0; tm < 4; ++tm) {
            bf16x8 ap = *(const bf16x8*)(Ps + (tm * 16 + l15) * 72 + ks * 32 + q8);
            #pragma unroll
            for (int tn = 0; tn < 2; ++tn)
                oc[tm][tn] = __builtin_amdgcn_mfma_f32_16x16x32_bf16(
                    ap, bv[tn], oc[tm][tn], 0, 0, 0);
        }
    }

    #pragma unroll
    for (int tm = 0; tm < 4; ++tm) {
        #pragma unroll
        for (int r = 0; r < 4; ++r) {
            int m = tm * 16 + q4 * 4 + r;
            if (m < 49) {
                __bf16* op = out + (size_t)(w * 49 + m) * C_DIM + head * 32;
                #pragma unroll
                for (int tn = 0; tn < 2; ++tn)
                    op[tn * 16 + l15] = (__bf16)(oc[tm][tn][r]);
            }
        }
    }
}

extern "C" void kernel_launch(void* const* d_in, const int* in_sizes, int n_in,
                              void* d_out, int out_size, void* d_ws, size_t ws_size,
                              hipStream_t stream) {
    const float* x     = (const float*)d_in[0];
    const float* n1w   = (const float*)d_in[1];
    const float* n1b   = (const float*)d_in[2];
    const float* qkvw  = (const float*)d_in[3];
    const float* qkvb  = (const float*)d_in[4];
    const float* rpb   = (const float*)d_in[5];
    const float* projw = (const float*)d_in[6];
    const float* projb = (const float*)d_in[7];
    const float* n2w   = (const float*)d_in[8];
    const float* n2b   = (const float*)d_in[9];
    const float* fc1w  = (const float*)d_in[10];
    const float* fc1b  = (const float*)d_in[11];
    const float* fc2w  = (const float*)d_in[12];
    const float* fc2b  = (const float*)d_in[13];
    float* out = (float*)d_out;
    char* ws = (char*)d_ws;

    // ws layout (total footprint exactly = R1-proven 192,675,840 bytes):
    //   bufA   @ 0           : 100352*192 bf16 = 38,535,168
    //   bufQ   @ 38,535,168  : 100352*576 bf16 (qkv), ends 154,140,672
    //   bufH   @ 38,535,168  : 100352*768 bf16 (hidden), ends 192,675,840
    //   pack   @ 192,151,552 : qkvw_b 221,184 | projw_b 73,728 | bias_g 57,624
    //     pack lives in bufH's TAIL: written step 0, last read step 4;
    //     bufH first written step 6 (clobbers pack after all uses). bufQ
    //     (ends 154.1MB) never reaches the pack. fc1/fc2 use fp32 weights
    //     directly (no safe scratch region exists during steps 6-7).
    __bf16* bufA = (__bf16*)ws;
    __bf16* bufQ = (__bf16*)(ws + 38535168);
    __bf16* bufH = (__bf16*)(ws + 38535168);
    __bf16* qkvw_b  = (__bf16*)(ws + 192151552);
    __bf16* projw_b = (__bf16*)(ws + 192151552 + 221184);
    float*  bias_g  = (float*) (ws + 192151552 + 221184 + 73728);

    // 0. weight conversions + bias expansion (tiny)
    cvt_kernel<<<(110592/8 + 255)/256, 256, 0, stream>>>(qkvw, qkvw_b, 110592/8);
    cvt_kernel<<<(36864/8  + 255)/256, 256, 0, stream>>>(projw, projw_b, 36864/8);
    bias_expand_kernel<<<(NHEADS*2401 + 255)/256, 256, 0, stream>>>(rpb, bias_g);

    // 1. LN1 + shift + window partition
    ln_kernel<1><<<NTOK / 4, 256, 0, stream>>>(x, n1w, n1b, bufA);
    // 2. QKV GEMM: (100352,192)x(192,576)
    gemm_kernel<0, 1><<<dim3(NTOK / 128, 9), 256, 0, stream>>>(
        bufA, qkvw_b, qkvb, bufQ, nullptr, 576, 192);
    // 3. windowed attention (MFMA)
    attn_mfma_kernel<<<NWIN * NHEADS / 4, 256, 0, stream>>>(bufQ, bias_g, bufA);
    // 4. proj GEMM + window reverse + residual -> d_out
    gemm_kernel<1, 1><<<dim3(NTOK / 128, 3), 256, 0, stream>>>(
        bufA, projw_b, projb, (void*)out, x, 192, 192);
    // 5. LN2
    ln_kernel<0><<<NTOK / 4, 256, 0, stream>>>(out, n2w, n2b, bufA);
    // 6. FC1 + GELU (fp32 weights, converted in staging)
    gemm_kernel<2, 0><<<dim3(NTOK / 128, 12), 256, 0, stream>>>(
        bufA, fc1w, fc1b, bufH, nullptr, 768, 192);
    // 7. FC2 + residual (fp32 weights)
    gemm_kernel<3, 0><<<dim3(NTOK / 128, 3), 256, 0, stream>>>(
        bufH, fc2w, fc2b, (void*)out, nullptr, 192, 768);
}

// Round 5
// 530.734 us; speedup vs baseline: 1.2779x; 1.0735x over previous
//
#include <hip/hip_runtime.h>
#include <hip/hip_bf16.h>
#include <cmath>

typedef float f32x4 __attribute__((ext_vector_type(4)));
typedef __bf16 bf16x8 __attribute__((ext_vector_type(8)));

#define WS_SZ 7
#define SHIFT 3
#define HGRID 56
#define C_DIM 192
#define NHEADS 6
#define HDIM 32
#define NTOK 100352   // 32 * 3136
#define NWIN 2048     // 32 * 8 * 8

// map window-space row (w*49+i) -> original token index (inverse roll by +SHIFT)
__device__ __forceinline__ int win_to_tok(int wrow) {
    int w = wrow / 49, i = wrow - w * 49;
    int b = w >> 6, rem = w & 63;
    int wy = rem >> 3, wx = rem & 7;
    int yi = i / 7, xi = i - yi * 7;
    int y = wy * 7 + yi + SHIFT; if (y >= HGRID) y -= HGRID;
    int x = wx * 7 + xi + SHIFT; if (x >= HGRID) x -= HGRID;
    return b * (HGRID * HGRID) + y * HGRID + x;
}

// ---------------- fp32 -> bf16 weight conversion (8 elems/thread) ----------------
__global__ __launch_bounds__(256)
void cvt_kernel(const float* __restrict__ src, __bf16* __restrict__ dst, int n8)
{
    int idx = blockIdx.x * 256 + threadIdx.x;
    if (idx >= n8) return;
    float4 a = ((const float4*)src)[idx * 2];
    float4 b = ((const float4*)src)[idx * 2 + 1];
    bf16x8 o;
    o[0] = (__bf16)a.x; o[1] = (__bf16)a.y; o[2] = (__bf16)a.z; o[3] = (__bf16)a.w;
    o[4] = (__bf16)b.x; o[5] = (__bf16)b.y; o[6] = (__bf16)b.z; o[7] = (__bf16)b.w;
    ((bf16x8*)dst)[idx] = o;
}

// ---------------- expand rel-pos bias -> bias_g[head][49][49] fp32 ----------------
__global__ __launch_bounds__(256)
void bias_expand_kernel(const float* __restrict__ rpb, float* __restrict__ bias_g)
{
    int idx = blockIdx.x * 256 + threadIdx.x;
    if (idx >= NHEADS * 2401) return;
    int h = idx / 2401, rem = idx - h * 2401;
    int i = rem / 49, j = rem - i * 49;
    int yi = i / 7, xi = i - yi * 7;
    int yj = j / 7, xj = j - yj * 7;
    int ri = (yi - yj + 6) * 13 + (xi - xj + 6);
    bias_g[idx] = rpb[ri * NHEADS + h];
}

// ---------------- LayerNorm (one wave per token) ----------------
template<int WINDOWED>
__global__ __launch_bounds__(256)
void ln_kernel(const float* __restrict__ x, const float* __restrict__ w,
               const float* __restrict__ b, __bf16* __restrict__ out)
{
    int r = blockIdx.x * 4 + (threadIdx.x >> 6);
    int lane = threadIdx.x & 63;
    int src = WINDOWED ? win_to_tok(r) : r;
    const float* xp = x + (size_t)src * C_DIM;
    float v0 = xp[lane], v1 = xp[lane + 64], v2 = xp[lane + 128];
    float s = v0 + v1 + v2;
    float sq = v0 * v0 + v1 * v1 + v2 * v2;
    #pragma unroll
    for (int off = 32; off; off >>= 1) {
        s  += __shfl_xor(s, off);
        sq += __shfl_xor(sq, off);
    }
    float mu = s * (1.f / C_DIM);
    float rs = rsqrtf(sq * (1.f / C_DIM) - mu * mu + 1e-5f);
    __bf16* op = out + (size_t)r * C_DIM;
    op[lane]       = (__bf16)((v0 - mu) * rs * w[lane]       + b[lane]);
    op[lane + 64]  = (__bf16)((v1 - mu) * rs * w[lane + 64]  + b[lane + 64]);
    op[lane + 128] = (__bf16)((v2 - mu) * rs * w[lane + 128] + b[lane + 128]);
}

// ---------------- GEMM: out = A(bf16, MxK) @ W(bf16, NxK)^T + bias ----------------
// Grid: x = n-tile (fast -> consecutive blocks share the A tile in L2), y = m-tile.
// MODE 0: store bf16. MODE 1: window-reverse scatter + residual -> fp32.
template<int MODE>
__global__ __launch_bounds__(256)
void gemm_kernel(const __bf16* __restrict__ A, const __bf16* __restrict__ W,
                 const float* __restrict__ bias, void* __restrict__ outp,
                 const float* __restrict__ resid, int N, int K)
{
    __shared__ __bf16 As[128 * 40];
    __shared__ __bf16 Bs[64 * 40];
    const int tid = threadIdx.x;
    const int wave = tid >> 6, lane = tid & 63;
    const int wm = wave >> 1, wn = wave & 1;
    const int l15 = lane & 15, q8 = (lane >> 4) << 3;
    const int m0 = blockIdx.y * 128, n0 = blockIdx.x * 64;

    f32x4 acc[4][2];
    f32x4 zero = {0.f, 0.f, 0.f, 0.f};
    #pragma unroll
    for (int i = 0; i < 4; i++)
        #pragma unroll
        for (int j = 0; j < 2; j++) acc[i][j] = zero;

    const int br = tid >> 2, bc = (tid & 3) << 3;
    for (int kt = 0; kt < K; kt += 32) {
        __syncthreads();
        #pragma unroll
        for (int it = 0; it < 2; it++) {
            int idx = it * 256 + tid;
            int r = idx >> 2, c = (idx & 3) << 3;
            *(uint4*)(&As[r * 40 + c]) =
                *(const uint4*)(A + (size_t)(m0 + r) * K + kt + c);
        }
        *(uint4*)(&Bs[br * 40 + bc]) =
            *(const uint4*)(W + (size_t)(n0 + br) * K + kt + bc);
        __syncthreads();
        bf16x8 af[4], bfr[2];
        #pragma unroll
        for (int fm = 0; fm < 4; fm++)
            af[fm] = *(const bf16x8*)(&As[(wm * 64 + fm * 16 + l15) * 40 + q8]);
        #pragma unroll
        for (int fn = 0; fn < 2; fn++)
            bfr[fn] = *(const bf16x8*)(&Bs[(wn * 32 + fn * 16 + l15) * 40 + q8]);
        #pragma unroll
        for (int fm = 0; fm < 4; fm++)
            #pragma unroll
            for (int fn = 0; fn < 2; fn++)
                acc[fm][fn] = __builtin_amdgcn_mfma_f32_16x16x32_bf16(
                    af[fm], bfr[fn], acc[fm][fn], 0, 0, 0);
    }

    const int l4 = lane >> 4;
    #pragma unroll
    for (int fm = 0; fm < 4; fm++) {
        #pragma unroll
        for (int fn = 0; fn < 2; fn++) {
            int c = n0 + wn * 32 + fn * 16 + l15;
            float bv = bias[c];
            #pragma unroll
            for (int r = 0; r < 4; r++) {
                int m = m0 + wm * 64 + fm * 16 + l4 * 4 + r;
                float v = acc[fm][fn][r] + bv;
                if (MODE == 0) {
                    ((__bf16*)outp)[(size_t)m * N + c] = (__bf16)v;
                } else {
                    int t = win_to_tok(m);
                    ((float*)outp)[(size_t)t * C_DIM + c] =
                        resid[(size_t)t * C_DIM + c] + v;
                }
            }
        }
    }
}

// ---------------- Fused MLP: out += GELU(A@W1^T + b1) @ W2^T + b2 ----------------
// 64-row tile, 256 threads (4 waves). Hidden 768 processed in 6 chunks of 128;
// hidden never touches HBM. W1/W2 frags direct from global (L2-resident bf16).
// GEMM1: wave wn computes S cols [wn*32, wn*32+32); GEMM2: out cols [wn*48, +48).
__global__ __launch_bounds__(256, 3)
void mlp_fused_kernel(const __bf16* __restrict__ A,   // NTOK x 192 (LN2 out)
                      const __bf16* __restrict__ w1,  // 768 x 192
                      const float* __restrict__ b1,
                      const __bf16* __restrict__ w2,  // 192 x 768
                      const float* __restrict__ b2,
                      float* __restrict__ out)        // NTOK x 192 fp32, RMW
{
    __shared__ __bf16 As[64 * 200];   // stride 200 elems (400B): 2-way banks only
    __shared__ __bf16 Hs[64 * 136];   // stride 136 elems (272B)
    const int tid = threadIdx.x;
    const int wn = tid >> 6, lane = tid & 63;
    const int l15 = lane & 15, q4 = lane >> 4, q8 = q4 << 3;
    const int m0 = blockIdx.x * 64;

    // stage A tile 64x192 (6 x 16B per thread)
    #pragma unroll
    for (int it = 0; it < 6; ++it) {
        int idx = it * 256 + tid;
        int r = idx / 24, c = (idx - r * 24) << 3;
        *(uint4*)(&As[r * 200 + c]) =
            *(const uint4*)(A + (size_t)(m0 + r) * 192 + c);
    }
    __syncthreads();

    f32x4 zero = {0.f, 0.f, 0.f, 0.f};
    f32x4 acc2[4][3];
    #pragma unroll
    for (int tm = 0; tm < 4; ++tm)
        #pragma unroll
        for (int tn = 0; tn < 3; ++tn) acc2[tm][tn] = zero;

    for (int ch = 0; ch < 6; ++ch) {
        const int h0 = ch * 128;
        // ---- GEMM1: S(64 x 32-per-wave) = As @ W1[h0+wn*32 ..][:]^T
        f32x4 acc1[4][2];
        #pragma unroll
        for (int tm = 0; tm < 4; ++tm)
            #pragma unroll
            for (int tn = 0; tn < 2; ++tn) acc1[tm][tn] = zero;
        #pragma unroll
        for (int kt = 0; kt < 6; ++kt) {
            bf16x8 bfr[2];
            #pragma unroll
            for (int tn = 0; tn < 2; ++tn)
                bfr[tn] = *(const bf16x8*)(w1 +
                    (size_t)(h0 + wn * 32 + tn * 16 + l15) * 192 + kt * 32 + q8);
            #pragma unroll
            for (int tm = 0; tm < 4; ++tm) {
                bf16x8 af = *(const bf16x8*)(&As[(tm * 16 + l15) * 200 + kt * 32 + q8]);
                #pragma unroll
                for (int tn = 0; tn < 2; ++tn)
                    acc1[tm][tn] = __builtin_amdgcn_mfma_f32_16x16x32_bf16(
                        af, bfr[tn], acc1[tm][tn], 0, 0, 0);
            }
        }
        // ---- GELU (x*sigmoid(1.702x)) -> Hs  (barrier: prev GEMM2 reads done)
        __syncthreads();
        #pragma unroll
        for (int tm = 0; tm < 4; ++tm) {
            #pragma unroll
            for (int tn = 0; tn < 2; ++tn) {
                int col = wn * 32 + tn * 16 + l15;
                float bv = b1[h0 + col];
                #pragma unroll
                for (int r = 0; r < 4; ++r) {
                    int row = tm * 16 + q4 * 4 + r;
                    float v = acc1[tm][tn][r] + bv;
                    float g = v / (1.f + __expf(-1.702f * v));
                    Hs[row * 136 + col] = (__bf16)g;
                }
            }
        }
        __syncthreads();
        // ---- GEMM2: acc2 += Hs @ W2[wn*48 ..][h0 ..]^T
        #pragma unroll
        for (int ks = 0; ks < 4; ++ks) {
            bf16x8 bfr[3];
            #pragma unroll
            for (int tn = 0; tn < 3; ++tn)
                bfr[tn] = *(const bf16x8*)(w2 +
                    (size_t)(wn * 48 + tn * 16 + l15) * 768 + h0 + ks * 32 + q8);
            #pragma unroll
            for (int tm = 0; tm < 4; ++tm) {
                bf16x8 af = *(const bf16x8*)(&Hs[(tm * 16 + l15) * 136 + ks * 32 + q8]);
                #pragma unroll
                for (int tn = 0; tn < 3; ++tn)
                    acc2[tm][tn] = __builtin_amdgcn_mfma_f32_16x16x32_bf16(
                        af, bfr[tn], acc2[tm][tn], 0, 0, 0);
            }
        }
    }

    // ---- epilogue: out += acc2 + b2
    #pragma unroll
    for (int tm = 0; tm < 4; ++tm) {
        #pragma unroll
        for (int tn = 0; tn < 3; ++tn) {
            int c = wn * 48 + tn * 16 + l15;
            float bv = b2[c];
            #pragma unroll
            for (int r = 0; r < 4; ++r) {
                int m = m0 + tm * 16 + q4 * 4 + r;
                float* p = out + (size_t)m * C_DIM + c;
                *p = *p + acc2[tm][tn][r] + bv;
            }
        }
    }
}

// ---------------- MFMA windowed attention: one wave per (window, head) ----------------
__global__ __launch_bounds__(256, 2)
void attn_mfma_kernel(const __bf16* __restrict__ qkv,
                      const float* __restrict__ bias_g,
                      __bf16* __restrict__ out)
{
    const int wave = threadIdx.x >> 6;
    const int lane = threadIdx.x & 63;
    const int pair = blockIdx.x * 4 + wave;       // 12288 pairs
    const int w = pair / 6, head = pair - (pair / 6) * 6;

    __shared__ __bf16 vsT_s[4][32 * 72];          // V^T: [d][j], stride 72
    __shared__ __bf16 Ps_s[4][64 * 72];           // P:   [i][j], stride 72
    __bf16* vsT = vsT_s[wave];
    __bf16* Ps  = Ps_s[wave];

    const int l15 = lane & 15, q4 = lane >> 4, q8 = q4 << 3;
    const size_t qbase = (size_t)w * 49 * 576 + head * 32;

    // stage V transposed: vsT[d][j] = V[j][d]; zero k-padding j in [49,64)
    {
        int d = lane & 31, jh = lane >> 5;
        #pragma unroll
        for (int it = 0; it < 25; ++it) {
            int j = it * 2 + jh;
            if (j < 49)
                vsT[d * 72 + j] = qkv[qbase + (size_t)j * 576 + 384 + d];
        }
        for (int idx = lane; idx < 32 * 15; idx += 64) {
            int dd = idx / 15, jj = 49 + (idx - dd * 15);
            vsT[dd * 72 + jj] = (__bf16)0.f;
        }
    }

    bf16x8 qf[4], kf[4];
    #pragma unroll
    for (int t = 0; t < 4; ++t) {
        int row = t * 16 + l15;
        int rq = row < 49 ? row : 48;
        qf[t] = *(const bf16x8*)(qkv + qbase + (size_t)rq * 576 + q8);
        kf[t] = *(const bf16x8*)(qkv + qbase + (size_t)rq * 576 + 192 + q8);
    }

    f32x4 sc[4][4];
    f32x4 zero = {0.f, 0.f, 0.f, 0.f};
    #pragma unroll
    for (int tm = 0; tm < 4; ++tm)
        #pragma unroll
        for (int tn = 0; tn < 4; ++tn) sc[tm][tn] = zero;
    #pragma unroll
    for (int tm = 0; tm < 4; ++tm)
        #pragma unroll
        for (int tn = 0; tn < 4; ++tn)
            sc[tm][tn] = __builtin_amdgcn_mfma_f32_16x16x32_bf16(
                qf[tm], kf[tn], sc[tm][tn], 0, 0, 0);

    const float scale = 0.17677669529663687f;      // 1/sqrt(32)
    const int hbase = head * 2401;
    #pragma unroll
    for (int tm = 0; tm < 4; ++tm) {
        #pragma unroll
        for (int r = 0; r < 4; ++r) {
            int i = tm * 16 + q4 * 4 + r;
            int ioff = hbase + (i < 49 ? i : 48) * 49;
            float v[4];
            #pragma unroll
            for (int tn = 0; tn < 4; ++tn) {
                int j = tn * 16 + l15;
                float bz = (j < 49) ? bias_g[ioff + (j < 49 ? j : 0)] : 0.f;
                float t = sc[tm][tn][r] * scale + bz;
                v[tn] = (j < 49) ? t : -1e30f;
            }
            float mx = fmaxf(fmaxf(v[0], v[1]), fmaxf(v[2], v[3]));
            mx = fmaxf(mx, __shfl_xor(mx, 1));
            mx = fmaxf(mx, __shfl_xor(mx, 2));
            mx = fmaxf(mx, __shfl_xor(mx, 4));
            mx = fmaxf(mx, __shfl_xor(mx, 8));
            float sm = 0.f;
            #pragma unroll
            for (int tn = 0; tn < 4; ++tn) {
                float e = __expf(v[tn] - mx);
                sc[tm][tn][r] = e;
                sm += e;
            }
            sm += __shfl_xor(sm, 1);
            sm += __shfl_xor(sm, 2);
            sm += __shfl_xor(sm, 4);
            sm += __shfl_xor(sm, 8);
            float inv = 1.f / sm;
            if (i < 49) {
                #pragma unroll
                for (int tn = 0; tn < 4; ++tn) {
                    int j = tn * 16 + l15;
                    Ps[i * 72 + j] = (__bf16)((j < 49) ? sc[tm][tn][r] * inv : 0.f);
                }
            }
        }
    }

    __syncthreads();

    f32x4 oc[4][2];
    #pragma unroll
    for (int tm = 0; tm < 4; ++tm)
        #pragma unroll
        for (int tn = 0; tn < 2; ++tn) oc[tm][tn] = zero;
    #pragma unroll
    for (int ks = 0; ks < 2; ++ks) {
        bf16x8 bv[2];
        #pragma unroll
        for (int tn = 0; tn < 2; ++tn)
            bv[tn] = *(const bf16x8*)(vsT + (tn * 16 + l15) * 72 + ks * 32 + q8);
        #pragma unroll
        for (int tm = 0; tm < 4; ++tm) {
            bf16x8 ap = *(const bf16x8*)(Ps + (tm * 16 + l15) * 72 + ks * 32 + q8);
            #pragma unroll
            for (int tn = 0; tn < 2; ++tn)
                oc[tm][tn] = __builtin_amdgcn_mfma_f32_16x16x32_bf16(
                    ap, bv[tn], oc[tm][tn], 0, 0, 0);
        }
    }

    #pragma unroll
    for (int tm = 0; tm < 4; ++tm) {
        #pragma unroll
        for (int r = 0; r < 4; ++r) {
            int m = tm * 16 + q4 * 4 + r;
            if (m < 49) {
                __bf16* op = out + (size_t)(w * 49 + m) * C_DIM + head * 32;
                #pragma unroll
                for (int tn = 0; tn < 2; ++tn)
                    op[tn * 16 + l15] = (__bf16)(oc[tm][tn][r]);
            }
        }
    }
}

extern "C" void kernel_launch(void* const* d_in, const int* in_sizes, int n_in,
                              void* d_out, int out_size, void* d_ws, size_t ws_size,
                              hipStream_t stream) {
    const float* x     = (const float*)d_in[0];
    const float* n1w   = (const float*)d_in[1];
    const float* n1b   = (const float*)d_in[2];
    const float* qkvw  = (const float*)d_in[3];
    const float* qkvb  = (const float*)d_in[4];
    const float* rpb   = (const float*)d_in[5];
    const float* projw = (const float*)d_in[6];
    const float* projb = (const float*)d_in[7];
    const float* n2w   = (const float*)d_in[8];
    const float* n2b   = (const float*)d_in[9];
    const float* fc1w  = (const float*)d_in[10];
    const float* fc1b  = (const float*)d_in[11];
    const float* fc2w  = (const float*)d_in[12];
    const float* fc2b  = (const float*)d_in[13];
    float* out = (float*)d_out;
    char* ws = (char*)d_ws;

    // ws layout — ALL regions disjoint, no lifetime aliasing (bufH eliminated):
    //   bufA    @ 0           : 100352*192 bf16 = 38,535,168
    //   bufQ    @ 38,535,168  : 100352*576 bf16 = 115,605,504 -> ends 154,140,672
    //   qkvw_b  @ 154,140,672 : 221,184
    //   projw_b @ 154,361,856 : 73,728
    //   fc1w_b  @ 154,435,584 : 294,912
    //   fc2w_b  @ 154,730,496 : 294,912
    //   bias_g  @ 155,025,408 : 57,624   -> ends 155,083,032 (< R1-proven 192.7MB)
    __bf16* bufA    = (__bf16*)ws;
    __bf16* bufQ    = (__bf16*)(ws + 38535168);
    __bf16* qkvw_b  = (__bf16*)(ws + 154140672);
    __bf16* projw_b = (__bf16*)(ws + 154361856);
    __bf16* fc1w_b  = (__bf16*)(ws + 154435584);
    __bf16* fc2w_b  = (__bf16*)(ws + 154730496);
    float*  bias_g  = (float*) (ws + 155025408);

    // 0. weight conversions + bias expansion (tiny)
    cvt_kernel<<<(110592/8 + 255)/256, 256, 0, stream>>>(qkvw, qkvw_b, 110592/8);
    cvt_kernel<<<(36864/8  + 255)/256, 256, 0, stream>>>(projw, projw_b, 36864/8);
    cvt_kernel<<<(147456/8 + 255)/256, 256, 0, stream>>>(fc1w, fc1w_b, 147456/8);
    cvt_kernel<<<(147456/8 + 255)/256, 256, 0, stream>>>(fc2w, fc2w_b, 147456/8);
    bias_expand_kernel<<<(NHEADS*2401 + 255)/256, 256, 0, stream>>>(rpb, bias_g);

    // 1. LN1 + shift + window partition
    ln_kernel<1><<<NTOK / 4, 256, 0, stream>>>(x, n1w, n1b, bufA);
    // 2. QKV GEMM (n-fast grid for A-tile L2 reuse)
    gemm_kernel<0><<<dim3(9, NTOK / 128), 256, 0, stream>>>(
        bufA, qkvw_b, qkvb, bufQ, nullptr, 576, 192);
    // 3. windowed attention (MFMA)
    attn_mfma_kernel<<<NWIN * NHEADS / 4, 256, 0, stream>>>(bufQ, bias_g, bufA);
    // 4. proj GEMM + window reverse + residual -> d_out
    gemm_kernel<1><<<dim3(3, NTOK / 128), 256, 0, stream>>>(
        bufA, projw_b, projb, (void*)out, x, 192, 192);
    // 5. LN2
    ln_kernel<0><<<NTOK / 4, 256, 0, stream>>>(out, n2w, n2b, bufA);
    // 6+7. fused MLP (FC1 + GELU + FC2 + residual), hidden never hits HBM
    mlp_fused_kernel<<<NTOK / 64, 256, 0, stream>>>(
        bufA, fc1w_b, fc1b, fc2w_b, fc2b, out);
}